// Round 8
// baseline (1938.251 us; speedup 1.0000x reference)
//
#include <hip/hip_runtime.h>

#define B_ 1024
#define T_ 1024
#define I_ 18
#define H_ 256
#define NCHUNK 16
#define NSLICE 16

typedef _Float16 f16;
typedef _Float16 f16x8 __attribute__((ext_vector_type(8)));
typedef float f32x4 __attribute__((ext_vector_type(4)));

#define MFMA16(a, b, c) __builtin_amdgcn_mfma_f32_16x16x32_f16((a), (b), (c), 0, 0, 0)
#define SB() __builtin_amdgcn_sched_barrier(0)

// ---------------- ws layout ----------------
#define H_SLOT (NCHUNK * 8 * 4 * 512)  // 262144 f16 = 512KB per ring slot
#define NFLAGS (NCHUNK * 4 * 32)
// ws: hb0[4] | hb1[2] | part | flags | ids | dec | (64B align) | xf[64MB opt]

struct TrueT { static constexpr bool value = true; };
struct FalseT { static constexpr bool value = false; };

__device__ __forceinline__ int hoff(int chunk, int kt, int m) {
  return (((chunk * 8) + kt) * 4 + m) * 512;
}

__global__ void init_ws(f16* __restrict__ hb, int* __restrict__ flg) {
  int i = blockIdx.x * blockDim.x + threadIdx.x;
  unsigned* p = (unsigned*)hb;
  for (int k = i; k < 3 * H_SLOT; k += gridDim.x * blockDim.x) p[k] = 0u;
  if (i < NFLAGS + 256 + 1) flg[i] = 0;
}

// x -> f16 A-fragment stream: frag (cw,p) is 512 f16; value(lane,j) =
// x[row = cw*16 + (lane&15)][t=p][k = (lane>>4)*8 + j], zero-padded K 18->32.
__global__ void prep_xfrag(const float* __restrict__ x, f16* __restrict__ xf) {
  int t = blockIdx.x * blockDim.x + threadIdx.x;  // 64*1024*64 threads
  int lane = t & 63;
  int p = (t >> 6) & (T_ - 1);
  int cw = t >> 16;
  int row = cw * 16 + (lane & 15);
  int kb = (lane >> 4) * 8;
  const float* src = x + ((size_t)row * T_ + p) * I_ + kb;
  f16 v[8];
#pragma unroll
  for (int j = 0; j < 8; ++j) v[j] = (kb + j < I_) ? (f16)src[j] : (f16)0.f;
  *(f16x8*)(xf + (size_t)t * 8) = *(f16x8*)v;
}

__device__ __forceinline__ float sigm(float v) {
  return __builtin_amdgcn_rcpf(1.f + __expf(-v));
}
__device__ __forceinline__ float tanh_fast(float v) {
  v = fmaxf(v, -15.f);
  float e = __expf(-2.f * v);
  return (1.f - e) * __builtin_amdgcn_rcpf(1.f + e);
}
__device__ __forceinline__ f16x8 cvt8(const float* q) {
  const f32x4* a = (const f32x4*)q;
  f32x4 u = a[0], v = a[1];
  f16x8 r;
  r[0] = (f16)u[0]; r[1] = (f16)u[1]; r[2] = (f16)u[2]; r[3] = (f16)u[3];
  r[4] = (f16)v[0]; r[5] = (f16)v[1]; r[6] = (f16)v[2]; r[7] = (f16)v[3];
  return r;
}

// FAST = XCD-local L2 path (plain WT stores, nt loads bypassing stale L1).
template <bool FAST>
__device__ __forceinline__ f16x8 ldh(const f16* p) {
  f16x8 r;
  if (FAST)
    asm volatile("global_load_dwordx4 %0, %1, off nt" : "=&v"(r) : "v"(p));
  else
    asm volatile("global_load_dwordx4 %0, %1, off sc0 sc1" : "=&v"(r) : "v"(p));
  return r;
}
__device__ __forceinline__ f16x8 ldg16(const f16* p) {  // plain cached
  f16x8 r;
  asm volatile("global_load_dwordx4 %0, %1, off" : "=&v"(r) : "v"(p));
  return r;
}
template <bool FAST>
__device__ __forceinline__ void sth(f16* p, f16 v) {
  unsigned u = (unsigned)__builtin_bit_cast(unsigned short, v);
  if (FAST)
    asm volatile("global_store_short %0, %1, off" ::"v"(p), "v"(u) : "memory");
  else
    asm volatile("global_store_short %0, %1, off sc0 sc1" ::"v"(p), "v"(u)
                 : "memory");
}
template <bool FAST>
__device__ __forceinline__ void stf(int* p, int v) {
  if (FAST)
    asm volatile("global_store_dword %0, %1, off" ::"v"(p), "v"(v) : "memory");
  else
    asm volatile("global_store_dword %0, %1, off sc0 sc1" ::"v"(p), "v"(v)
                 : "memory");
}
template <bool FAST>
__device__ __forceinline__ int ldf(const int* p) {  // flag load + drain
  int r;
  if (FAST)
    asm volatile("global_load_dword %0, %1, off nt\n\ts_waitcnt vmcnt(0)"
                 : "=&v"(r) : "v"(p) : "memory");
  else
    asm volatile("global_load_dword %0, %1, off sc0 sc1\n\ts_waitcnt vmcnt(0)"
                 : "=&v"(r) : "v"(p) : "memory");
  return r;
}
__device__ __forceinline__ int ld_sys(const int* p) {
  int r;
  asm volatile("global_load_dword %0, %1, off sc0 sc1\n\ts_waitcnt vmcnt(0)"
               : "=&v"(r) : "v"(p) : "memory");
  return r;
}
__device__ __forceinline__ void st_sys(int* p, int v) { stf<false>(p, v); }
__device__ __forceinline__ f32x4 ldx4(const float* p) {
  f32x4 r;
  asm volatile("global_load_dwordx4 %0, %1, off" : "=&v"(r) : "v"(p));
  return r;
}

// 256 blocks x 512 threads; chunk = blockIdx&15, slice = blockIdx>>4.
// waves 0-3: layer-0 recurrence (critical). waves 4-7: layer-1 (trails).
__global__ __launch_bounds__(512, 2) void gru_main(
    const float* __restrict__ x, const float* __restrict__ Wih0,
    const float* __restrict__ Whh0, const float* __restrict__ Wih1,
    const float* __restrict__ Whh1, const float* __restrict__ bih0,
    const float* __restrict__ bhh0, const float* __restrict__ bih1,
    const float* __restrict__ bhh1, const float* __restrict__ fcw,
    f16* __restrict__ hb0, f16* __restrict__ hb1, float* __restrict__ part,
    int* __restrict__ flags, int* __restrict__ ids, int* __restrict__ dec,
    const f16* __restrict__ xf, int xf_ok) {
  __shared__ f16 whh1_l[24 * 512];  // 24KB: W_hh1 slice fragments

  const int tid = threadIdx.x;
  const int wv = tid >> 6, lane = tid & 63;
  const int w = wv & 3;
  const bool isL0 = wv < 4;
  const int lrow = lane & 15, lgrp = lane >> 4;
  const int chunk = blockIdx.x & 15, slice = blockIdx.x >> 4;
  const int c = slice * 16 + lrow;

  for (int idx = tid; idx < 24 * 64; idx += 512) {
    int f = idx >> 6, l = idx & 63;
    int g = f >> 3, kt = f & 7;
    int n = g * H_ + slice * 16 + (l & 15);
    ((f16x8*)whh1_l)[idx] = cvt8(&Whh1[n * H_ + kt * 32 + (l >> 4) * 8]);
  }

  const int* fpoll = flags + (chunk * 4 + w) * 32 + (lane & 31);
  const int rbase = chunk * 64 + w * 16;
  const int s_kt = slice >> 1;
  const int s_off = 128 * ((slice & 1) * 2 + (lrow >> 3)) + (lrow & 7);

  // ---- runtime XCD-placement verification -> global fast/slow decision ----
  {
    unsigned xcc;
    asm volatile("s_getreg_b32 %0, hwreg(HW_REG_XCC_ID)" : "=s"(xcc));
    if (tid == 0) st_sys(ids + blockIdx.x, (int)xcc + 1);
    if (blockIdx.x == 0 && wv == 0) {
      int ok, guard = 0;
      for (;;) {
        int v0 = ld_sys(ids + lane * 4 + 0), v1 = ld_sys(ids + lane * 4 + 1);
        int v2 = ld_sys(ids + lane * 4 + 2), v3 = ld_sys(ids + lane * 4 + 3);
        ok = (v0 && v1 && v2 && v3);
        if (__all(ok)) { ok = 1; break; }
        if (++guard > (1 << 16)) { ok = 0; break; }
        __builtin_amdgcn_s_sleep(8);
      }
      int verdict = 1;
      if (ok) {
        int eq = 1;
        if (lane < 16) {
          int r0 = ld_sys(ids + lane);
          for (int s = 1; s < 16; ++s)
            eq &= (ld_sys(ids + s * 16 + lane) == r0);
        }
        verdict = __all(eq) ? 2 : 1;
      }
      if (lane == 0) st_sys(dec, verdict);
    }
  }
  int decision = 1;
  {
    int g = 0;
    for (;;) {
      int d = ld_sys(dec);
      if (d) { decision = d; break; }
      if (++g > (1 << 20)) break;
      __builtin_amdgcn_s_sleep(8);
    }
  }
  __syncthreads();

  if (isL0) {
    // =========================== LAYER-0 WAVES ===========================
    f16x8 wfA[27];
#pragma unroll
    for (int g = 0; g < 3; ++g) {
      int n = g * H_ + c;
      f16 v[8];
#pragma unroll
      for (int j = 0; j < 8; ++j) {
        int k = lgrp * 8 + j;
        v[j] = (k < I_) ? (f16)Wih0[n * I_ + k] : (f16)0.f;
      }
      wfA[g] = *(f16x8*)v;
    }
#pragma unroll
    for (int g = 0; g < 3; ++g)
#pragma unroll
      for (int kt = 0; kt < 8; ++kt)
        wfA[3 + g * 8 + kt] =
            cvt8(&Whh0[(g * H_ + c) * H_ + kt * 32 + lgrp * 8]);

    const float bR0 = bih0[c] + bhh0[c], bZ0 = bih0[H_ + c] + bhh0[H_ + c];
    const float bI0 = bih0[2 * H_ + c], bH0 = bhh0[2 * H_ + c];
    float h0r[4] = {0.f, 0.f, 0.f, 0.f};
    int* fpost0 = flags + (chunk * 4 + w) * 32 + slice;
    const f16* xfw = xf + (size_t)(chunk * 4 + w) * T_ * 512 + lane * 8;
    const float* xrow = x + (size_t)(rbase + lrow) * T_ * I_;
    const int o1 = (lgrp == 0) ? 0 : (lgrp == 1) ? 8 : (lgrp == 2) ? 14 : 0;
    const int o2 = (lgrp == 0) ? 4 : (lgrp == 1) ? 12 : 0;
    int dead = 0;

    auto loop0 = [&](auto FC, auto XFC) {
      constexpr bool F = decltype(FC)::value;
      constexpr bool XV = decltype(XFC)::value;
      asm volatile("s_waitcnt vmcnt(0)" ::: "memory");
      SB();
      f16x8 xcur;
      f32x4 xA1, xA2;
      if (XV) {
        xcur = ldg16(xfw);  // frag p=0
      } else {
        xA1 = ldx4(xrow + o1);
        xA2 = ldx4(xrow + o2);
      }
      asm volatile("s_waitcnt vmcnt(0)" ::: "memory");
      SB();
      for (int p = 0; p < T_; ++p) {
        if (p > 0 && !dead) {
          const int tgt = (lane & 16) ? (p - 3) : p;
          int guard = 0;
          for (;;) {
            int v = ldf<F>(fpoll);
            if (__all(v >= tgt)) break;
            if (++guard > (1 << 18)) { dead = 1; break; }
          }
        }
        SB();
        __builtin_amdgcn_s_setprio(1);
        f16x8 ah0[8];
        {
          const f16* b0 = hb0 + (size_t)((p - 1) & 3) * H_SLOT +
                          hoff(chunk, 0, w) + lane * 8;
#pragma unroll
          for (int kt = 0; kt < 8; ++kt) ah0[kt] = ldh<F>(b0 + kt * 2048);
        }
        f16x8 xnext;
        if (XV)  // x(p+1): issued now, consumed NEXT phase (never drained hot)
          xnext = ldg16(xfw + (size_t)((p + 1 < T_) ? p + 1 : p) * 512);
        SB();
        f16x8 ax;
        if (XV) {
          ax = xcur;
        } else {
          float s0 = (lgrp == 2) ? xA1[2] : xA1[0];
          float s1 = (lgrp == 2) ? xA1[3] : xA1[1];
          ax[0] = (f16)s0;     ax[1] = (f16)s1;
          ax[2] = (f16)xA1[2]; ax[3] = (f16)xA1[3];
          ax[4] = (f16)xA2[0]; ax[5] = (f16)xA2[1];
          ax[6] = (f16)xA2[2]; ax[7] = (f16)xA2[3];
        }
        f32x4 aR = {bR0, bR0, bR0, bR0}, aZ = {bZ0, bZ0, bZ0, bZ0};
        f32x4 aI = {bI0, bI0, bI0, bI0}, aH = {bH0, bH0, bH0, bH0};
        aR = MFMA16(ax, wfA[0], aR);
        aZ = MFMA16(ax, wfA[1], aZ);
        aI = MFMA16(ax, wfA[2], aI);
        SB();
        if (XV)
          asm volatile("s_waitcnt vmcnt(5)" ::: "memory");  // ah0[0..3]
        else
          asm volatile("s_waitcnt vmcnt(4)" ::: "memory");
        SB();
#pragma unroll
        for (int kt = 0; kt < 4; ++kt) {
          aR = MFMA16(ah0[kt], wfA[3 + kt], aR);
          aZ = MFMA16(ah0[kt], wfA[11 + kt], aZ);
          aH = MFMA16(ah0[kt], wfA[19 + kt], aH);
        }
        SB();
        if (XV)
          asm volatile("s_waitcnt vmcnt(1)" ::: "memory");  // ah0[4..7]
        else
          asm volatile("s_waitcnt vmcnt(0)" ::: "memory");
        SB();
#pragma unroll
        for (int kt = 4; kt < 8; ++kt) {
          aR = MFMA16(ah0[kt], wfA[3 + kt], aR);
          aZ = MFMA16(ah0[kt], wfA[11 + kt], aZ);
          aH = MFMA16(ah0[kt], wfA[19 + kt], aH);
        }
        {
          f16* d0 = hb0 + (size_t)(p & 3) * H_SLOT + hoff(chunk, s_kt, w) +
                    s_off;
#pragma unroll
          for (int i = 0; i < 4; ++i) {
            float rr = sigm(aR[i]);
            float zz = sigm(aZ[i]);
            float nn = tanh_fast(aI[i] + rr * aH[i]);
            h0r[i] = (1.f - zz) * nn + zz * h0r[i];
            sth<F>(d0 + (lgrp * 4 + i) * 8, (f16)h0r[i]);
          }
        }
        if (!XV) {  // legacy: x(p+1) after stores, vmcnt(2) keeps it flying
          int tn = (p + 1 < T_) ? p + 1 : T_ - 1;
          const float* px = xrow + (size_t)tn * I_;
          xA1 = ldx4(px + o1);
          xA2 = ldx4(px + o2);
        }
        SB();
        if (XV)
          asm volatile("s_waitcnt vmcnt(0)" ::: "memory");  // acks; xnext old
        else
          asm volatile("s_waitcnt vmcnt(2)" ::: "memory");
        SB();
        if (lane == 0) stf<F>(fpost0, p + 1);
        __builtin_amdgcn_s_setprio(0);
        if (XV) xcur = xnext;
      }
    };
    if (decision == 2) {
      if (xf_ok) loop0(TrueT{}, TrueT{});
      else loop0(TrueT{}, FalseT{});
    } else {
      if (xf_ok) loop0(FalseT{}, TrueT{});
      else loop0(FalseT{}, FalseT{});
    }
  } else {
    // =========================== LAYER-1 WAVES ===========================
    f16x8 wfB[24];
#pragma unroll
    for (int g = 0; g < 3; ++g)
#pragma unroll
      for (int kt = 0; kt < 8; ++kt)
        wfB[g * 8 + kt] =
            cvt8(&Wih1[(g * H_ + c) * H_ + kt * 32 + lgrp * 8]);

    const float bR1 = bih1[c] + bhh1[c], bZ1 = bih1[H_ + c] + bhh1[H_ + c];
    const float bI1 = bih1[2 * H_ + c], bH1 = bhh1[2 * H_ + c];
    const float fw = fcw[c];
    float h1r[4] = {0.f, 0.f, 0.f, 0.f};
    int* fpost1 = flags + (chunk * 4 + w) * 32 + 16 + slice;
    int dead = 0;

    auto loop1 = [&](auto FC) {
      constexpr bool F = decltype(FC)::value;
      for (int p = 1; p <= T_; ++p) {
        if (!dead) {  // stage A: flag1 >= p-1
          int guard = 0;
          for (;;) {
            int v = ldf<F>(fpoll);
            if (__all((lane & 16) ? (v >= p - 1) : 1)) break;
            if (++guard > (1 << 18)) { dead = 1; break; }
          }
        }
        SB();
        f16x8 ah1[8];
        {
          const f16* b1 = hb1 + (size_t)(p & 1) * H_SLOT +
                          hoff(chunk, 0, w) + lane * 8;
#pragma unroll
          for (int kt = 0; kt < 8; ++kt) ah1[kt] = ldh<F>(b1 + kt * 2048);
        }
        SB();
        if (!dead) {  // stage B: flag0 >= p (drains ah1 under the wait)
          int guard = 0;
          for (;;) {
            int v = ldf<F>(fpoll);
            if (__all((lane & 16) ? 1 : (v >= p))) break;
            if (++guard > (1 << 18)) { dead = 1; break; }
          }
        }
        SB();
        f16x8 ah0[8];
        {
          const f16* b0 = hb0 + (size_t)((p - 1) & 3) * H_SLOT +
                          hoff(chunk, 0, w) + lane * 8;
#pragma unroll
          for (int kt = 0; kt < 8; ++kt) ah0[kt] = ldh<F>(b0 + kt * 2048);
        }
        SB();
        f32x4 aR = {bR1, bR1, bR1, bR1}, aZ = {bZ1, bZ1, bZ1, bZ1};
        f32x4 aI = {bI1, bI1, bI1, bI1}, aH = {bH1, bH1, bH1, bH1};
#pragma unroll
        for (int kt = 0; kt < 8; ++kt) {  // hh1 (LDS B) while ah0 flies
          f16x8 br = *(const f16x8*)&whh1_l[(0 * 8 + kt) * 512 + lane * 8];
          f16x8 bz = *(const f16x8*)&whh1_l[(1 * 8 + kt) * 512 + lane * 8];
          f16x8 bn = *(const f16x8*)&whh1_l[(2 * 8 + kt) * 512 + lane * 8];
          aR = MFMA16(ah1[kt], br, aR);
          aZ = MFMA16(ah1[kt], bz, aZ);
          aH = MFMA16(ah1[kt], bn, aH);
        }
        SB();
        asm volatile("s_waitcnt vmcnt(0)" ::: "memory");  // ah0 done
        SB();
#pragma unroll
        for (int kt = 0; kt < 8; ++kt) {
          aR = MFMA16(ah0[kt], wfB[kt], aR);
          aZ = MFMA16(ah0[kt], wfB[8 + kt], aZ);
          aI = MFMA16(ah0[kt], wfB[16 + kt], aI);
        }
        {
          f16* d1 = hb1 + (size_t)((p - 1) & 1) * H_SLOT +
                    hoff(chunk, s_kt, w) + s_off;
#pragma unroll
          for (int i = 0; i < 4; ++i) {
            float rr = sigm(aR[i]);
            float zz = sigm(aZ[i]);
            float nn = tanh_fast(aI[i] + rr * aH[i]);
            h1r[i] = (1.f - zz) * nn + zz * h1r[i];
            sth<F>(d1 + (lgrp * 4 + i) * 8, (f16)h1r[i]);
          }
        }
        SB();
        asm volatile("s_waitcnt vmcnt(0)" ::: "memory");
        SB();
        if (lane == 0) stf<F>(fpost1, p);
      }
    };
    if (decision == 2) loop1(TrueT{});
    else loop1(FalseT{});

    float tmp[4];
#pragma unroll
    for (int i = 0; i < 4; ++i) {
      float v = h1r[i] * fw;
#pragma unroll
      for (int m = 1; m < 16; m <<= 1) v += __shfl_xor(v, m);
      tmp[i] = v;
    }
    if (lrow == 0) {
#pragma unroll
      for (int i = 0; i < 4; ++i)
        part[(size_t)(rbase + lgrp * 4 + i) * 16 + slice] = tmp[i];
    }
  }
}

__global__ void fc_reduce(const float* __restrict__ part,
                          const float* __restrict__ fcb,
                          float* __restrict__ out) {
  int r = blockIdx.x * blockDim.x + threadIdx.x;
  if (r < B_) {
    float s = fcb[0];
#pragma unroll
    for (int i = 0; i < 16; ++i) s += part[r * 16 + i];
    out[r] = s;
  }
}

extern "C" void kernel_launch(void* const* d_in, const int* in_sizes, int n_in,
                              void* d_out, int out_size, void* d_ws, size_t ws_size,
                              hipStream_t stream) {
  const float* x    = (const float*)d_in[0];
  const float* Wih0 = (const float*)d_in[1];
  const float* Whh0 = (const float*)d_in[2];
  const float* bih0 = (const float*)d_in[3];
  const float* bhh0 = (const float*)d_in[4];
  const float* Wih1 = (const float*)d_in[5];
  const float* Whh1 = (const float*)d_in[6];
  const float* bih1 = (const float*)d_in[7];
  const float* bhh1 = (const float*)d_in[8];
  const float* fcw  = (const float*)d_in[9];
  const float* fcb  = (const float*)d_in[10];

  f16* hb0 = (f16*)d_ws;
  f16* hb1 = hb0 + (size_t)4 * H_SLOT;
  float* part = (float*)(hb1 + (size_t)2 * H_SLOT);
  int* flags = (int*)(part + 1024 * 16);
  int* ids = flags + NFLAGS;
  int* dec = ids + 256;

  size_t base_bytes = (size_t)(6 * H_SLOT) * 2 + 1024 * 16 * 4 +
                      (size_t)(NFLAGS + 256 + 1) * 4;
  size_t xf_off = (base_bytes + 63) & ~(size_t)63;
  size_t xf_bytes = (size_t)64 * 1024 * 1024;  // 64*1024 frags * 1KB
  int xf_ok = (ws_size >= xf_off + xf_bytes) ? 1 : 0;
  f16* xf = (f16*)((char*)d_ws + xf_off);

  init_ws<<<1024, 256, 0, stream>>>(hb0, flags);
  if (xf_ok) prep_xfrag<<<16384, 256, 0, stream>>>(x, xf);
  gru_main<<<256, 512, 0, stream>>>(x, Wih0, Whh0, Wih1, Whh1, bih0, bhh0,
                                    bih1, bhh1, fcw, hb0, hb1, part, flags,
                                    ids, dec, xf, xf_ok);
  fc_reduce<<<4, 256, 0, stream>>>(part, fcb, (float*)d_out);
}